// Round 6
// baseline (130.129 us; speedup 1.0000x reference)
//
#include <hip/hip_runtime.h>

// Depthwise Gaussian blur K=121, replicate pad, separable, fp32.
// R6: FUSED single kernel. Block = 8 rows x full 512 cols. Vertical conv
// streams its 128-row window from global (float2/lane, L2-served re-read),
// intermediate lives in LDS (12-float padded groups + 60/76-col replicate
// halo), horizontal conv (R4-proven 16-col/lane rotating window) writes out.
// Full-width tile => zero redundant vertical FLOPs (vblur commutes with
// column replication). No tmp buffer, one dispatch.

#define HH      512
#define WW      512
#define PLANE   (512 * 512)
#define NIMG    24
#define HPG_ROW 972                 // 81 groups * (8 real + 4 pad) floats

__device__ __forceinline__ void make_weights(const float* __restrict__ sigma,
                                             float* __restrict__ wlds, int tid) {
    const float s = sigma[0] * 8.0f + 16.0f;
    const float inv2v = 1.0f / (2.0f * s * s);
    float sum = 0.0f;
    #pragma unroll
    for (int k = 0; k <= 120; ++k) {
        const float c = (float)k - 60.0f;
        sum += __expf(-c * c * inv2v);
    }
    if (tid < 128) {
        float g = 0.0f;
        if (tid < 121) {
            const float c = (float)tid - 60.0f;
            g = __expf(-c * c * inv2v);
        }
        wlds[tid] = g / sum;        // taps 121..127 exactly 0
    }
}

// Vertical octet: prefetch next 8 window rows (float2, clamped), 8 taps x
// 8 output rows. window[i] == input row r0-60+KO*8+i.
#define V_OCT(CUR, NXT, KO)                                               \
    { *(float4*)&wq[0] = *(const float4*)&wlds[(KO) * 8];                 \
      *(float4*)&wq[4] = *(const float4*)&wlds[(KO) * 8 + 4];             \
      _Pragma("unroll")                                                   \
      for (int ki = 0; ki < 8; ++ki) {                                    \
          int rr = r0 - 52 + (KO) * 8 + ki;                               \
          rr = rr < 0 ? 0 : (rr > HH - 1 ? HH - 1 : rr);                  \
          NXT[ki] = *(const float2*)&src[(size_t)rr * WW];                \
          const float wk = wq[ki];                                        \
          _Pragma("unroll")                                               \
          for (int j = 0; j < 8; ++j) {                                   \
              const int idx = ki + j;                                     \
              const float2 v = (idx < 8) ? CUR[idx] : NXT[idx - 8];       \
              vac[j].x += wk * v.x; vac[j].y += wk * v.y;                 \
          }                                                               \
      }                                                                   \
    }

#define LOADG(DST, G)                                                     \
    { *(float4*)&DST[0] = *(const float4*)&bs[(G) * 12];                  \
      *(float4*)&DST[4] = *(const float4*)&bs[(G) * 12 + 4]; }

#define H_OCT(W0, W1, W2, W3, KO)                                         \
    { LOADG(W3, (KO) + 3)                                                 \
      *(float4*)&wq[0] = *(const float4*)&wlds[(KO) * 8];                 \
      *(float4*)&wq[4] = *(const float4*)&wlds[(KO) * 8 + 4];             \
      _Pragma("unroll")                                                   \
      for (int ki = 0; ki < 8; ++ki) {                                    \
          const float wk = wq[ki];                                        \
          _Pragma("unroll")                                               \
          for (int j = 0; j < 16; ++j) {                                  \
              const int idx = ki + j;                                     \
              const float v = (idx < 8) ? W0[idx]                         \
                            : (idx < 16) ? W1[idx - 8] : W2[idx - 16];    \
              acc[j] += wk * v;                                           \
          }                                                               \
      }                                                                   \
    }

__global__ __launch_bounds__(256, 4) void blur_fused(
        const float* __restrict__ x, const float* __restrict__ sigma,
        float* __restrict__ out) {
    __shared__ float sm[8 * HPG_ROW];                // 31.1 KB
    __shared__ float wlds[128];
    const int tid = threadIdx.x;
    const int r0  = blockIdx.x * 8;                  // output rows r0..r0+7
    const int c0  = tid * 2;                         // this thread's 2 cols
    const float* __restrict__ src = x + (size_t)blockIdx.y * PLANE + c0;

    // ---- vertical: 8 rows x 2 cols per thread, global-streamed window ----
    float2 wa[8], wb[8], vac[8];
    float  wq[8];
    #pragma unroll
    for (int m = 0; m < 8; ++m) {                    // rows r0-60..r0-53
        int rr = r0 - 60 + m;
        rr = rr < 0 ? 0 : rr;
        wa[m] = *(const float2*)&src[(size_t)rr * WW];
    }
    make_weights(sigma, wlds, tid);                  // overlaps loads in flight
    #pragma unroll
    for (int j = 0; j < 8; ++j) vac[j] = make_float2(0.f, 0.f);
    __syncthreads();                                 // wlds ready

    #pragma unroll 1
    for (int ko = 0; ko < 16; ko += 2) {
        V_OCT(wa, wb, ko)
        V_OCT(wb, wa, ko + 1)
    }

    // write intermediate into padded groups at halo offset +60
    {
        const int p  = c0 + 60;                      // even; stays in-group
        const int la = (p >> 3) * 12 + (p & 7);
        #pragma unroll
        for (int j = 0; j < 8; ++j)
            *(float2*)&sm[j * HPG_ROW + la] = vac[j];
    }
    __syncthreads();

    // ---- replicate halo: padded idx 0..59 <- idx 60; 572..647 <- idx 571 ---
    if (tid < 136) {
        const int p    = (tid < 60) ? tid : 512 + tid;        // dest padded idx
        const int dsta = (p >> 3) * 12 + (p & 7);
        const int srca = (tid < 60) ? (7 * 12 + 4)            // idx 60
                                    : (71 * 12 + 3);          // idx 571
        #pragma unroll
        for (int r = 0; r < 8; ++r)
            sm[r * HPG_ROW + dsta] = sm[r * HPG_ROW + srca];
    }
    __syncthreads();

    // ---- horizontal: 16 cols per lane, rotating 4-octet window -----------
    const int r = tid >> 5;                          // 0..7
    const int L = tid & 31;                          // cols 16L..16L+15
    const float* __restrict__ bs = sm + r * HPG_ROW + L * 24;  // group 2L

    float w0[8], w1[8], w2[8], w3[8];
    float acc[16];
    #pragma unroll
    for (int j = 0; j < 16; ++j) acc[j] = 0.0f;

    LOADG(w0, 0)
    LOADG(w1, 1)
    LOADG(w2, 2)

    #pragma unroll 1
    for (int ko = 0; ko < 16; ko += 4) {
        H_OCT(w0, w1, w2, w3, ko)
        H_OCT(w1, w2, w3, w0, ko + 1)
        H_OCT(w2, w3, w0, w1, ko + 2)
        H_OCT(w3, w0, w1, w2, ko + 3)
    }

    float* __restrict__ dst = out + (size_t)blockIdx.y * PLANE
                                  + (size_t)(r0 + r) * WW + L * 16;
    *(float4*)(dst)      = make_float4(acc[0],  acc[1],  acc[2],  acc[3]);
    *(float4*)(dst + 4)  = make_float4(acc[4],  acc[5],  acc[6],  acc[7]);
    *(float4*)(dst + 8)  = make_float4(acc[8],  acc[9],  acc[10], acc[11]);
    *(float4*)(dst + 12) = make_float4(acc[12], acc[13], acc[14], acc[15]);
}

extern "C" void kernel_launch(void* const* d_in, const int* in_sizes, int n_in,
                              void* d_out, int out_size, void* d_ws, size_t ws_size,
                              hipStream_t stream) {
    const float* x     = (const float*)d_in[0];
    const float* sigma = (const float*)d_in[1];
    float* out = (float*)d_out;
    blur_fused<<<dim3(HH / 8, NIMG), dim3(256), 0, stream>>>(x, sigma, out);
}

// Round 7
// 117.873 us; speedup vs baseline: 1.1040x; 1.1040x over previous
//
#include <hip/hip_runtime.h>

// Depthwise Gaussian blur K=121, replicate pad, separable, fp32. FUSED.
// R7: (a) XCD swizzle -- contiguous 192-tile span per XCD so overlapping
// vertical windows hit the same L2 (R6 FETCH was 190MB = 25MB x 8 XCDs);
// (b) conflict-free H phase: lane handles two 8-col spans (group bases L,
// L+32) so b128 bases (12L mod 32) cover all 8 slots -> 32 banks at the
// b128 floor (R6: 4 slots, 9M conflict cycles).

#define HH      512
#define WW      512
#define PLANE   (512 * 512)
#define NIMG    24
#define HPG_ROW 984                 // 82 groups * (8 real + 4 pad) floats

__device__ __forceinline__ void make_weights(const float* __restrict__ sigma,
                                             float* __restrict__ wlds, int tid) {
    const float s = sigma[0] * 8.0f + 16.0f;
    const float inv2v = 1.0f / (2.0f * s * s);
    float sum = 0.0f;
    #pragma unroll
    for (int k = 0; k <= 120; ++k) {
        const float c = (float)k - 60.0f;
        sum += __expf(-c * c * inv2v);
    }
    if (tid < 128) {
        float g = 0.0f;
        if (tid < 121) {
            const float c = (float)tid - 60.0f;
            g = __expf(-c * c * inv2v);
        }
        wlds[tid] = g / sum;        // taps 121..127 exactly 0
    }
}

// Vertical octet: prefetch next 8 window rows (float2, clamped), 8 taps x
// 8 output rows.
#define V_OCT(CUR, NXT, KO)                                               \
    { *(float4*)&wq[0] = *(const float4*)&wlds[(KO) * 8];                 \
      *(float4*)&wq[4] = *(const float4*)&wlds[(KO) * 8 + 4];             \
      _Pragma("unroll")                                                   \
      for (int ki = 0; ki < 8; ++ki) {                                    \
          int rr = r0 - 52 + (KO) * 8 + ki;                               \
          rr = rr < 0 ? 0 : (rr > HH - 1 ? HH - 1 : rr);                  \
          NXT[ki] = *(const float2*)&src[(size_t)rr * WW];                \
          const float wk = wq[ki];                                        \
          _Pragma("unroll")                                               \
          for (int j = 0; j < 8; ++j) {                                   \
              const int idx = ki + j;                                     \
              const float2 v = (idx < 8) ? CUR[idx] : NXT[idx - 8];       \
              vac[j].x += wk * v.x; vac[j].y += wk * v.y;                 \
          }                                                               \
      }                                                                   \
    }

#define LOADG(DST, G)                                                     \
    { *(float4*)&DST[0] = *(const float4*)&bs[(G) * 12];                  \
      *(float4*)&DST[4] = *(const float4*)&bs[(G) * 12 + 4]; }

// One octet, TWO 8-col spans (A: groups L+.., B: groups L+32+..)
#define H_OCT2(A0, A1, A2, A3, B0, B1, B2, B3, KO)                        \
    { LOADG(A3, L + (KO) + 3)                                             \
      LOADG(B3, L + 32 + (KO) + 3)                                        \
      *(float4*)&wq[0] = *(const float4*)&wlds[(KO) * 8];                 \
      *(float4*)&wq[4] = *(const float4*)&wlds[(KO) * 8 + 4];             \
      _Pragma("unroll")                                                   \
      for (int ki = 0; ki < 8; ++ki) {                                    \
          const float wk = wq[ki];                                        \
          _Pragma("unroll")                                               \
          for (int j = 0; j < 8; ++j) {                                   \
              const int idx = ki + j;                                     \
              const float vA = (idx < 8) ? A0[idx]                        \
                             : (idx < 16) ? A1[idx - 8] : A2[idx - 16];   \
              const float vB = (idx < 8) ? B0[idx]                        \
                             : (idx < 16) ? B1[idx - 8] : B2[idx - 16];   \
              accA[j] += wk * vA;                                         \
              accB[j] += wk * vB;                                         \
          }                                                               \
      }                                                                   \
    }

__global__ __launch_bounds__(256, 4) void blur_fused(
        const float* __restrict__ x, const float* __restrict__ sigma,
        float* __restrict__ out) {
    __shared__ float sm[8 * HPG_ROW];                // 30.8 KB
    __shared__ float wlds[128];
    const int tid = threadIdx.x;

    // XCD swizzle: linear id -> contiguous 192-tile span per XCD (%8 rr).
    const int lid   = blockIdx.x + gridDim.x * blockIdx.y;   // 0..1535
    const int tile  = (lid & 7) * 192 + (lid >> 3);
    const int r0    = (tile & 63) * 8;               // output rows r0..r0+7
    const int plane = tile >> 6;

    const int c0 = tid * 2;                          // this thread's 2 cols
    const float* __restrict__ src = x + (size_t)plane * PLANE + c0;

    // ---- vertical: 8 rows x 2 cols per thread, global-streamed window ----
    float2 wa[8], wb[8], vac[8];
    float  wq[8];
    #pragma unroll
    for (int m = 0; m < 8; ++m) {                    // rows r0-60..r0-53
        int rr = r0 - 60 + m;
        rr = rr < 0 ? 0 : rr;
        wa[m] = *(const float2*)&src[(size_t)rr * WW];
    }
    make_weights(sigma, wlds, tid);                  // overlaps loads in flight
    #pragma unroll
    for (int j = 0; j < 8; ++j) vac[j] = make_float2(0.f, 0.f);
    __syncthreads();                                 // wlds ready

    #pragma unroll 1
    for (int ko = 0; ko < 16; ko += 2) {
        V_OCT(wa, wb, ko)
        V_OCT(wb, wa, ko + 1)
    }

    // write intermediate into padded groups at halo offset +60
    {
        const int p  = c0 + 60;                      // 60..570, even
        const int la = (p >> 3) * 12 + (p & 7);
        #pragma unroll
        for (int j = 0; j < 8; ++j)
            *(float2*)&sm[j * HPG_ROW + la] = vac[j];
    }
    __syncthreads();

    // ---- halo: idx 0..59 <- 60; 572..647 <- 571; zero 648..655 -----------
    if (tid < 144) {
        int p, srca;
        if (tid < 60)       { p = tid;       srca = 7 * 12 + 4;  }  // idx 60
        else if (tid < 136) { p = 512 + tid; srca = 71 * 12 + 3; }  // idx 571
        else                { p = 512 + tid; srca = -1;          }  // zero
        const int dsta = (p >> 3) * 12 + (p & 7);
        #pragma unroll
        for (int r = 0; r < 8; ++r)
            sm[r * HPG_ROW + dsta] = (srca < 0) ? 0.0f
                                                : sm[r * HPG_ROW + srca];
    }
    __syncthreads();

    // ---- horizontal: two 8-col spans per lane, rotating 4-octet windows --
    const int r = tid >> 5;                          // 0..7
    const int L = tid & 31;                          // span A cols 8L.., B +256
    const float* __restrict__ bs = sm + r * HPG_ROW;

    float a0[8], a1[8], a2[8], a3[8];
    float b0[8], b1[8], b2[8], b3[8];
    float accA[8], accB[8];
    #pragma unroll
    for (int j = 0; j < 8; ++j) { accA[j] = 0.0f; accB[j] = 0.0f; }

    LOADG(a0, L)      LOADG(b0, L + 32)
    LOADG(a1, L + 1)  LOADG(b1, L + 33)
    LOADG(a2, L + 2)  LOADG(b2, L + 34)

    #pragma unroll 1
    for (int ko = 0; ko < 16; ko += 4) {
        H_OCT2(a0, a1, a2, a3, b0, b1, b2, b3, ko)
        H_OCT2(a1, a2, a3, a0, b1, b2, b3, b0, ko + 1)
        H_OCT2(a2, a3, a0, a1, b2, b3, b0, b1, ko + 2)
        H_OCT2(a3, a0, a1, a2, b3, b0, b1, b2, ko + 3)
    }

    float* __restrict__ dst = out + (size_t)plane * PLANE
                                  + (size_t)(r0 + r) * WW + L * 8;
    *(float4*)(dst)        = make_float4(accA[0], accA[1], accA[2], accA[3]);
    *(float4*)(dst + 4)    = make_float4(accA[4], accA[5], accA[6], accA[7]);
    *(float4*)(dst + 256)  = make_float4(accB[0], accB[1], accB[2], accB[3]);
    *(float4*)(dst + 260)  = make_float4(accB[4], accB[5], accB[6], accB[7]);
}

extern "C" void kernel_launch(void* const* d_in, const int* in_sizes, int n_in,
                              void* d_out, int out_size, void* d_ws, size_t ws_size,
                              hipStream_t stream) {
    const float* x     = (const float*)d_in[0];
    const float* sigma = (const float*)d_in[1];
    float* out = (float*)d_out;
    blur_fused<<<dim3(HH / 8, NIMG), dim3(256), 0, stream>>>(x, sigma, out);
}